// Round 6
// baseline (780.281 us; speedup 1.0000x reference)
//
#include <hip/hip_runtime.h>
#include <math.h>
#include <float.h>

#define B_   16
#define N_   4096
#define CIN  3
#define COUT 64
#define KNN  20
#define EPS_ 1e-5
#define SVC  24     // survivor slots per lane (LDS [SVC][512] u16)

// ---------------------------------------------------------------------------
// Workspace layout (5.5MB proven-safe footprint):
//   [0,   216): double stats[27]
//   [256, 768): float scale[64], shift[64]
//   [1024, +B*N*KNN*4): int idx[B*N*KNN]
//   [5243904, +B*N*4): int perm[B*N]
//
// knn LDS (80KB dynamic, 2 blocks/CU), QUARTER-MAJOR SoA:
//   [0,  16K): xs_q[4][1024] f32   [16K,32K): ys_q   [32K,48K): zs_q
//   [48K,56K): j16_q[4][1024] u16
//   [56K,80K): svb[SVC][512] u16 (stores quarter-index t; bank = tid/2, free)
//   merge-scratch double view overlays [0, 40K) after scans complete.
//
// r5 post-mortem: bk[20] f64 live across the scan loop -> compiler spilled
// (VGPR_Count=44 < 40 needed for bk alone) -> every insert was a scratch
// round-trip. This round: ub computed WITHOUT bk (max of 20 prefill d's ==
// d-part of bk[19], bit-identical); scan is append-only (~12 live VGPRs);
// bk exists only from the drain onward. __launch_bounds__(512,4) budgets
// 128 VGPRs so the drain never spills.
// ---------------------------------------------------------------------------

__device__ __forceinline__ unsigned expand10(unsigned v) {
    v = (v | (v << 16)) & 0x030000FFu;
    v = (v | (v << 8))  & 0x0300F00Fu;
    v = (v | (v << 4))  & 0x030C30C3u;
    v = (v | (v << 2))  & 0x09249249u;
    return v;
}
__device__ __forceinline__ unsigned quant10(float v) {
    int q = (int)((v + 4.0f) * 128.0f);
    return (unsigned)min(1023, max(0, q));
}

// ===========================================================================
// Kernel 0: per-batch Morton COUNTING sort (unchanged, verified)
// ===========================================================================
__global__ __launch_bounds__(1024) void morton_bucket_kernel(
    const float* __restrict__ x, int* __restrict__ perm)
{
    __shared__ int hist[1024];
    __shared__ int scanbuf[1024];
    __shared__ int offs[1024];
    const int b = blockIdx.x, tid = threadIdx.x;
    const float* xb = x + (size_t)b * N_ * CIN;

    hist[tid] = 0;
    __syncthreads();

    int keys[4];
#pragma unroll
    for (int i = 0; i < 4; ++i) {
        int p = tid + i * 1024;
        float v0 = xb[p * 3 + 0], v1 = xb[p * 3 + 1], v2 = xb[p * 3 + 2];
        unsigned m = (expand10(quant10(v0)) << 2) |
                     (expand10(quant10(v1)) << 1) |
                      expand10(quant10(v2));
        keys[i] = (int)(m >> 20);          // top 10 bits
        atomicAdd(&hist[keys[i]], 1);
    }
    __syncthreads();

    int v = hist[tid];
    scanbuf[tid] = v;
    __syncthreads();
    for (int off = 1; off < 1024; off <<= 1) {   // Hillis-Steele inclusive
        int t = (tid >= off) ? scanbuf[tid - off] : 0;
        __syncthreads();
        scanbuf[tid] += t;
        __syncthreads();
    }
    offs[tid] = scanbuf[tid] - v;                // exclusive base
    __syncthreads();

#pragma unroll
    for (int i = 0; i < 4; ++i) {
        int p = tid + i * 1024;
        int pos = atomicAdd(&offs[keys[i]], 1);
        perm[b * N_ + pos] = p;
    }
}

// ===========================================================================
// Kernel 1: exact-match KNN — phase-split filter-then-select.
// Correctness chain (r4/r5 harness-verified, restructured without changing
// the selected set):
//  1. ub = max exact-f32 d over the 20 prefill candidates
//         == d-part of bk[19] after prefill (max key <-> max d): identical
//         bound to the verified r4/r5 decode, no f64 involved.
//  2. winner w: key_w <= max of ANY 20-key subset => d_w <= ub. No eps.
//  3. scan (prefill-masked, append-only): d <= ub -> store quarter-index.
//  4. bk built AFTER the scan: prefill inserts + survivor drain; overflow
//     lanes (cnt > SVC) do a filtered re-scan instead of the drain (each
//     candidate inserted exactly once -> no duplicate keys).
//  5. 2-round merge / extraction / BN stats: byte-identical verified code.
// ===========================================================================
__global__ __launch_bounds__(512, 4) void knn_f64_kernel(
    const float* __restrict__ x, const int* __restrict__ perm,
    int* __restrict__ idx_out, double* __restrict__ stats)
{
    extern __shared__ __align__(16) char smem[];
    float* xs_q = (float*)smem;                            // [4][1024]
    float* ys_q = (float*)(smem + 16384);                  // [4][1024]
    float* zs_q = (float*)(smem + 32768);                  // [4][1024]
    unsigned short* j16_q = (unsigned short*)(smem + 49152); // [4][1024]
    unsigned short* svb   = (unsigned short*)(smem + 57344); // [SVC][512]
    double* scr = (double*)smem;                           // merge view

    const int b    = blockIdx.y;
    const int tid  = threadIdx.x;
    const int wave = tid >> 6;
    const int lane = tid & 63;
    const int r    = wave >> 2;     // row-group 0..1
    const int q    = wave & 3;      // interleave class: positions p&3==q
    const float* xb = x + (size_t)b * N_ * CIN;

    for (int p = tid; p < N_; p += 512) {
        int j = perm[b * N_ + p];                // coalesced
        int qq = p & 3, tt = p >> 2;
        xs_q[qq * 1024 + tt] = xb[j * 3 + 0];
        ys_q[qq * 1024 + tt] = xb[j * 3 + 1];
        zs_q[qq * 1024 + tt] = xb[j * 3 + 2];
        j16_q[qq * 1024 + tt] = (unsigned short)j;
    }
    __syncthreads();

    const int rowg = blockIdx.x * 128 + r * 64;  // wave's first row pos
    const int rp   = rowg + lane;
    const int rq = rp & 3, rt = rp >> 2;
    const float xfx = xs_q[rq * 1024 + rt];
    const float xfy = ys_q[rq * 1024 + rt];
    const float xfz = zs_q[rq * 1024 + rt];
    const int jrow  = j16_q[rq * 1024 + rt];
    const float sqi = __fadd_rn(__fadd_rn(__fmul_rn(xfx, xfx),
                                          __fmul_rn(xfy, xfy)),
                                __fmul_rn(xfz, xfz));

    // exact f32 distance: bit-identical to the np/jax reference expansion
    auto mkd3 = [&](float px, float py, float pz) -> float {
        float sqj = __fadd_rn(__fadd_rn(__fmul_rn(px, px),
                                        __fmul_rn(py, py)),
                              __fmul_rn(pz, pz));
        float dot = __fadd_rn(__fadd_rn(__fmul_rn(xfx, px),
                                        __fmul_rn(xfy, py)),
                              __fmul_rn(xfz, pz));
        return __fsub_rn(__fadd_rn(sqi, sqj), __fmul_rn(2.0f, dot));
    };
    // quarter-local accessors (this wave only touches quarter q + row reads)
    const float* xq = xs_q + q * 1024;
    const float* yq = ys_q + q * 1024;
    const float* zq = zs_q + q * 1024;
    const unsigned short* jq = j16_q + q * 1024;

    auto mkkeyt = [&](int t) -> double {     // key for quarter-index t
        float d = mkd3(xq[t], yq[t], zq[t]);
        unsigned u = __float_as_uint(d);
        unsigned s = u ^ (0x80000000u | (unsigned)((int)u >> 31));
        return fma((double)s, 4096.0, (double)(unsigned)jq[t]);
    };

    const int ta = rowg >> 2;            // wave-uniform anchor

    // ---- phase 1: ub = max exact d over the 20 prefill candidates ----
    // (== d-part of bk[19] after the verified prefill: max key <-> max d)
    float ub = -1e30f;
#pragma unroll
    for (int k = 0; k < KNN; ++k) {
        int t = (ta + k) & 1023;
        ub = fmaxf(ub, mkd3(xq[t], yq[t], zq[t]));
    }

    // ---- phase 2: append-only filtered scan (tiny register liveness) ----
    unsigned cnt = 0;
    for (int t = 0; t < 1024; t += 4) {
        float4 xv = *(const float4*)(xq + t);     // wave-uniform b128
        float4 yv = *(const float4*)(yq + t);
        float4 zv = *(const float4*)(zq + t);
        float d0 = mkd3(xv.x, yv.x, zv.x);
        float d1 = mkd3(xv.y, yv.y, zv.y);
        float d2 = mkd3(xv.z, yv.z, zv.z);
        float d3 = mkd3(xv.w, yv.w, zv.w);
#pragma unroll
        for (int i = 0; i < 4; ++i) {
            int ti = t + i;
            float d = (i == 0) ? d0 : (i == 1) ? d1 : (i == 2) ? d2 : d3;
            bool notpre = ((unsigned)((ti - ta) & 1023) >= 20u);
            bool h = notpre && (d <= ub);
            if (h && cnt < SVC) svb[cnt * 512 + tid] = (unsigned short)ti;
            cnt += (unsigned)h;
        }
    }

    // ---- phase 3: build bk (verified machinery, born after the scan) ----
    double bk[KNN];
#pragma unroll
    for (int k = 0; k < KNN; ++k) bk[k] = 1e300;     // sentinels (sorted)

    auto insert = [&](double key) {                  // VERBATIM verified
        if (key < bk[KNN - 1]) {
            double m = key;
#pragma unroll
            for (int k = 0; k < KNN; ++k) {
                double old = bk[k];
                bk[k] = fmin(m, old);
                m     = fmax(old, m);
            }
        }
    };

#pragma unroll
    for (int k = 0; k < KNN; ++k)
        insert(mkkeyt((ta + k) & 1023));             // prefill keys

    if (cnt <= (unsigned)SVC) {
        for (unsigned i = 0; i < cnt; ++i)
            insert(mkkeyt((int)svb[i * 512 + tid]));
    } else {
        // overflow (rare): filtered re-scan replaces the drain entirely —
        // every admitted candidate inserted exactly once, no duplicates.
        for (int t = 0; t < 1024; ++t) {
            bool notpre = ((unsigned)((t - ta) & 1023) >= 20u);
            if (notpre && (mkd3(xq[t], yq[t], zq[t]) <= ub))
                insert(mkkeyt(t));
        }
    }
    __syncthreads();    // scans done; SoA tile dead -> scr valid

    // ---- merge round A: q1 -> slot0, q3 -> slot1 (verbatim verified) ----
    if (q & 1) {
        int base = ((r * 2 + (q >> 1)) * 64 + lane) * KNN;
#pragma unroll
        for (int k = 0; k < KNN; ++k) scr[base + k] = bk[k];
    }
    __syncthreads();
    if (!(q & 1)) {                 // q0 absorbs q1; q2 absorbs q3
        int base = ((r * 2 + (q >> 1)) * 64 + lane) * KNN;
#pragma unroll
        for (int k = 0; k < KNN; ++k) insert(scr[base + k]);
    }
    __syncthreads();
    if (q == 2) {
        int base = ((r * 2 + 1) * 64 + lane) * KNN;
#pragma unroll
        for (int k = 0; k < KNN; ++k) scr[base + k] = bk[k];
    }
    __syncthreads();
    if (q == 0) {
        int base = ((r * 2 + 1) * 64 + lane) * KNN;
#pragma unroll
        for (int k = 0; k < KNN; ++k) insert(scr[base + k]);

        const long long row = (long long)b * N_ + jrow;
        int bi[KNN];
#pragma unroll
        for (int k = 0; k < KNN; ++k) {
            double sp = trunc(bk[k] * (1.0 / 4096.0));
            bi[k] = (int)(bk[k] - sp * 4096.0);
        }
#pragma unroll
        for (int k = 0; k < KNN; ++k) idx_out[row * KNN + k] = bi[k];

        float acc[27];
#pragma unroll
        for (int t = 0; t < 27; ++t) acc[t] = 0.0f;
#pragma unroll
        for (int k = 0; k < KNN; ++k) {
            const float* pj = xb + bi[k] * 3;
            float e[6] = { xfx, xfy, xfz,
                           pj[0] - xfx, pj[1] - xfy, pj[2] - xfz };
            int t = 6;
#pragma unroll
            for (int a = 0; a < 6; ++a) {
                acc[a] += e[a];
#pragma unroll
                for (int bb = a; bb < 6; ++bb) acc[t++] += e[a] * e[bb];
            }
        }
#pragma unroll
        for (int t = 0; t < 27; ++t) {
            float v = acc[t];
            v += __shfl_down(v, 32); v += __shfl_down(v, 16);
            v += __shfl_down(v, 8);  v += __shfl_down(v, 4);
            v += __shfl_down(v, 2);  v += __shfl_down(v, 1);
            acc[t] = v;
        }
        if (lane == 0) {
#pragma unroll
            for (int t = 0; t < 27; ++t) atomicAdd(&stats[t], (double)acc[t]);
        }
    }
}

// ===========================================================================
// Kernel 2: fold stats -> per-channel scale/shift (unchanged, verified)
// ===========================================================================
__global__ void bn_prep_kernel(
    const double* __restrict__ stats,
    const float* __restrict__ w1, const float* __restrict__ b1,
    const float* __restrict__ gamma, const float* __restrict__ beta,
    float* __restrict__ scale_shift)
{
    const int c = threadIdx.x;
    double s[6], S[6][6];
#pragma unroll
    for (int a = 0; a < 6; ++a) s[a] = stats[a];
    int t = 6;
#pragma unroll
    for (int a = 0; a < 6; ++a)
#pragma unroll
        for (int bb = a; bb < 6; ++bb) { S[a][bb] = stats[t]; S[bb][a] = stats[t]; ++t; }

    const double M = (double)B_ * N_ * KNN;
    double wc[6];
#pragma unroll
    for (int j = 0; j < 6; ++j) wc[j] = (double)w1[j * COUT + c];
    const double b1c = (double)b1[c];

    double sw = 0.0;
#pragma unroll
    for (int j = 0; j < 6; ++j) sw += s[j] * wc[j];
    double mean = sw / M + b1c;

    double qq = 0.0;
#pragma unroll
    for (int a = 0; a < 6; ++a)
#pragma unroll
        for (int bb = 0; bb < 6; ++bb) qq += S[a][bb] * wc[a] * wc[bb];
    double ex2 = (qq + 2.0 * b1c * sw) / M + b1c * b1c;
    double var = ex2 - mean * mean;

    double sc = (double)gamma[c] / sqrt(var + (double)EPS_);
    double sh = (double)beta[c] - mean * sc;
    scale_shift[c]        = (float)sc;
    scale_shift[COUT + c] = (float)sh;
}

// ===========================================================================
// Kernel 3: fused edge->lin1->BN->ReLU->lin2->max via split-bf16 MFMA
// (unchanged, verified: wave-private LDS, no barriers, 24 MFMA/k-tile)
// ===========================================================================
typedef __attribute__((ext_vector_type(8))) short short8;
typedef __attribute__((ext_vector_type(4))) float f32x4;

__device__ __forceinline__ unsigned short f2bf_rn(float f) {
    unsigned u = __float_as_uint(f);
    unsigned lsb = (u >> 16) & 1u;
    return (unsigned short)((u + 0x7FFFu + lsb) >> 16);
}
__device__ __forceinline__ float bf2f(unsigned short h) {
    return __uint_as_float(((unsigned)h) << 16);
}

__global__ __launch_bounds__(256) void mlp_max_kernel(
    const float* __restrict__ x, const int* __restrict__ idx,
    const float* __restrict__ w1, const float* __restrict__ b1,
    const float* __restrict__ scale_shift,
    const float* __restrict__ w2, const float* __restrict__ b2,
    float* __restrict__ out)
{
    __shared__ __align__(16) unsigned short hbuf[4][2][16][136];

    const int tid  = threadIdx.x;
    const int wv   = tid >> 6;
    const int lane = tid & 63;
    const int g    = lane >> 4;      // 16-lane group (k-chunk select)
    const int r15  = lane & 15;      // row (A) / col (B,C) within tile

    const int R     = (blockIdx.x * 4 + wv) * 16;   // wave's first row
    const int bbase = (R >> 12) << 12;              // batch slab start row

    const int c  = lane;
    const float sc = scale_shift[c];
    const float sh = scale_shift[COUT + c];
    float w1p[6];
#pragma unroll
    for (int j = 0; j < 6; ++j) w1p[j] = w1[j * COUT + c] * sc;
    const float b1p = fmaf(b1[c], sc, sh);
    const float dw0 = w1p[0] - w1p[3];
    const float dw1 = w1p[1] - w1p[4];
    const float dw2 = w1p[2] - w1p[5];

    short8 Wh[2][4], Wl[2][4];
#pragma unroll
    for (int t = 0; t < 2; ++t)
#pragma unroll
        for (int n = 0; n < 4; ++n) {
            short8 hv, lv;
#pragma unroll
            for (int jj = 0; jj < 8; ++jj) {
                float w = w2[(t * 32 + g * 8 + jj) * COUT + n * 16 + r15];
                unsigned short hi = f2bf_rn(w);
                unsigned short lo = f2bf_rn(w - bf2f(hi));
                hv[jj] = (short)hi;
                lv[jj] = (short)lo;
            }
            Wh[t][n] = hv;
            Wl[t][n] = lv;
        }

    float base[16];
#pragma unroll
    for (int r = 0; r < 16; ++r) {
        const float* pi = x + (size_t)(R + r) * 3;
        float v = b1p;
        v = fmaf(pi[0], dw0, v);
        v = fmaf(pi[1], dw1, v);
        v = fmaf(pi[2], dw2, v);
        base[r] = v;
    }

    const int* idxp = idx + (size_t)R * KNN;

    f32x4 mx[4];
#pragma unroll
    for (int n = 0; n < 4; ++n) {
        mx[n][0] = -INFINITY; mx[n][1] = -INFINITY;
        mx[n][2] = -INFINITY; mx[n][3] = -INFINITY;
    }

    for (int k = 0; k < KNN; ++k) {
        unsigned short* hb = &hbuf[wv][k & 1][0][0];

#pragma unroll
        for (int r = 0; r < 16; ++r) {
            int j = idxp[r * KNN + k];                    // wave-uniform
            const float* pj = x + (size_t)(bbase + j) * 3;
            float h = base[r];
            h = fmaf(pj[0], w1p[3], h);
            h = fmaf(pj[1], w1p[4], h);
            h = fmaf(pj[2], w1p[5], h);
            h = fmaxf(h, 0.0f);
            unsigned short hi = f2bf_rn(h);
            unsigned short lo = f2bf_rn(h - bf2f(hi));
            hb[r * 136 + c]      = hi;
            hb[r * 136 + 64 + c] = lo;
        }

        const unsigned short* rpnt = hb + r15 * 136;
        short8 Ah0 = *(const short8*)(rpnt + g * 8);
        short8 Ah1 = *(const short8*)(rpnt + 32 + g * 8);
        short8 Al0 = *(const short8*)(rpnt + 64 + g * 8);
        short8 Al1 = *(const short8*)(rpnt + 96 + g * 8);

#pragma unroll
        for (int n = 0; n < 4; ++n) {
            f32x4 a = {0.0f, 0.0f, 0.0f, 0.0f};
            a = __builtin_amdgcn_mfma_f32_16x16x32_bf16(Ah0, Wh[0][n], a, 0, 0, 0);
            a = __builtin_amdgcn_mfma_f32_16x16x32_bf16(Ah1, Wh[1][n], a, 0, 0, 0);
            a = __builtin_amdgcn_mfma_f32_16x16x32_bf16(Al0, Wh[0][n], a, 0, 0, 0);
            a = __builtin_amdgcn_mfma_f32_16x16x32_bf16(Al1, Wh[1][n], a, 0, 0, 0);
            a = __builtin_amdgcn_mfma_f32_16x16x32_bf16(Ah0, Wl[0][n], a, 0, 0, 0);
            a = __builtin_amdgcn_mfma_f32_16x16x32_bf16(Ah1, Wl[1][n], a, 0, 0, 0);
            mx[n][0] = fmaxf(mx[n][0], a[0]);
            mx[n][1] = fmaxf(mx[n][1], a[1]);
            mx[n][2] = fmaxf(mx[n][2], a[2]);
            mx[n][3] = fmaxf(mx[n][3], a[3]);
        }
    }

    float b2v[4];
#pragma unroll
    for (int n = 0; n < 4; ++n) b2v[n] = b2[n * 16 + r15];
#pragma unroll
    for (int n = 0; n < 4; ++n)
#pragma unroll
        for (int rr = 0; rr < 4; ++rr)
            out[(size_t)(R + g * 4 + rr) * COUT + n * 16 + r15] =
                mx[n][rr] + b2v[n];
}

// ===========================================================================
extern "C" void kernel_launch(void* const* d_in, const int* in_sizes, int n_in,
                              void* d_out, int out_size, void* d_ws, size_t ws_size,
                              hipStream_t stream)
{
    const float* x     = (const float*)d_in[0];
    const float* w1    = (const float*)d_in[2];
    const float* b1    = (const float*)d_in[3];
    const float* gamma = (const float*)d_in[4];
    const float* beta  = (const float*)d_in[5];
    const float* w2    = (const float*)d_in[6];
    const float* b2    = (const float*)d_in[7];
    float* out = (float*)d_out;

    char*   ws          = (char*)d_ws;
    double* stats       = (double*)ws;
    float*  scale_shift = (float*)(ws + 256);
    int*    idx         = (int*)(ws + 1024);
    int*    perm        = (int*)(ws + 1024 + (size_t)B_ * N_ * KNN * 4);

    // one-time opt-in for >64KB dynamic LDS; host-side, graph-capture-safe.
    static int _lds_once = []() {
        (void)hipFuncSetAttribute((const void*)knn_f64_kernel,
                                  hipFuncAttributeMaxDynamicSharedMemorySize,
                                  131072);
        return 0;
    }();
    (void)_lds_once;

    hipMemsetAsync(stats, 0, 27 * sizeof(double), stream);
    morton_bucket_kernel<<<B_, 1024, 0, stream>>>(x, perm);
    knn_f64_kernel<<<dim3(32, 16), 512, 81920, stream>>>(x, perm, idx, stats);
    bn_prep_kernel<<<1, COUT, 0, stream>>>(stats, w1, b1, gamma, beta, scale_shift);
    mlp_max_kernel<<<(B_ * N_) / 64, 256, 0, stream>>>(x, idx, w1, b1, scale_shift,
                                                       w2, b2, out);
}